// Round 11
// baseline (316.344 us; speedup 1.0000x reference)
//
#include <hip/hip_runtime.h>
#include <stdint.h>

// Problem constants (fixed by the reference setup_inputs)
#define BATCH 128
#define SEQN  384
#define SEQM  384
#define DIM   128
#define KINF   1000000.0f                 // reference pseudo-infinity (nat units)
#define LOG2E  1.4426950408889634f
#define LN2    0.6931471805599453f
#define KINF2  (KINF * LOG2E)             // pseudo-infinity in base-2-scaled units

// Fused producer/consumer geometry: 2 batches per block, ring per batch.
#define RING    100                       // LDS ring capacity in D-columns (per batch)
#define RSTRIDE 392                       // ushorts per ring column (conflict-free banks)

// hardware base-2 transcendentals (v_exp_f32 / v_log_f32)
#define EXP2F(x) __builtin_amdgcn_exp2f(x)
#define LOG2F(x) __builtin_amdgcn_logf(x)

#define WG __HIP_MEMORY_SCOPE_WORKGROUP

typedef __attribute__((ext_vector_type(8))) short bf16x8;   // 8 bf16 = 4 VGPRs (MFMA A/B frag)
typedef __attribute__((ext_vector_type(4))) float f32x4;    // MFMA C/D frag

__device__ __forceinline__ unsigned short bf16_rne(float x) {
    uint32_t u = __float_as_uint(x);
    u += 0x7FFFu + ((u >> 16) & 1u);
    return (unsigned short)(u >> 16);
}
__device__ __forceinline__ uint32_t bf16_pair(float x, float y) {
    uint32_t ux = __float_as_uint(x); ux += 0x7FFFu + ((ux >> 16) & 1u);
    uint32_t uy = __float_as_uint(y); uy += 0x7FFFu + ((uy >> 16) & 1u);
    return (ux >> 16) | (uy & 0xFFFF0000u);
}

// DPP wavefront-shift-right-by-1: lane n <- lane n-1 (== __shfl_up(x,1,64)).
__device__ __forceinline__ float dpp_shfl_up1(float x) {
    return __int_as_float(__builtin_amdgcn_update_dpp(
        0, (int)__float_as_uint(x), 0x138 /*WAVE_SHR1*/, 0xF, 0xF, false));
}

union frag_u { bf16x8 v; uint32_t u[4]; };

// ---------------------------------------------------------------------------
// Fused kernel: 64 blocks = 128 batches x (2 per block), 8 waves, 1 block/CU.
//   waves 0,4     : DP consumers for batch 2*bx+0 / 2*bx+1. BOTH map to SIMD0
//                   (wave->SIMD = id%4): their independent streams interleave,
//                   filling each other's in-order dependency stalls (the r10
//                   fixed cost ~435cyc/slot). Consumer body = r10 verbatim
//                   (1-col/lane skew, DPP boundary, COLPASS math unchanged).
//   waves 1-3     : producers batch0 (pidx 0..2, 8 si-groups each, r2 body).
//   waves 5-7     : producers batch1.
// Ring = 100 cols/batch (2x78.4KB = 160KB LDS). Wrap windows are ~5 slots, so
// the consumer publishes cons_sl EVERY slot (relaxed; per-wave DS FIFO order
// makes this safe) + a release fence every 8 slots. Producer wrap gate:
// chunk k >= 3 waits cons_sl >= 32k-9 (last read of destroyed col 32k-69 is
// lane63's refill at slot 32k-10; +1 margin). Pads (cols 384..387 -> slots
// 84..87) by pidx0 after chunk 11, gated cons_sl >= 352 (needed at slot 380).
// ---------------------------------------------------------------------------
__global__ __launch_bounds__(512) void fused_dtw(
        const float* __restrict__ A, const float* __restrict__ B,
        float* __restrict__ out) {
    __shared__ __align__(16) unsigned short ring[2][RING * RSTRIDE]; // 156,800 B
    __shared__ __align__(16) float normA[2][SEQN];                   //   3,072 B
    __shared__ int prod_done[2][16];
    __shared__ int cons_sl[2];

    const int bx   = blockIdx.x;
    const int tid  = threadIdx.x;
    const int wv   = tid >> 6;
    const int lane = tid & 63;

    if (tid < 32) prod_done[tid >> 4][tid & 15] = 0;
    if (tid == 32) cons_sl[0] = -1;
    if (tid == 33) cons_sl[1] = -1;
    __syncthreads();                       // only block-wide sync in the kernel

    const int b   = wv >> 2;               // batch half: waves 0-3 -> 0, 4-7 -> 1
    const int bat = 2 * bx + b;

    if ((wv & 3) != 0) {
        // ========== PRODUCERS (waves 1,2,3 / 5,6,7 -> pidx 0..2 per batch) ===
        const int pidx  = (wv & 3) - 1;
        const int sbase = pidx * 8;        // this wave's 8 si-groups (of 24)
        const int l16 = lane & 15, q = lane >> 4;
        const float* __restrict__ Ab = A + (long)bat * SEQN * DIM;
        const float* __restrict__ Bb = B + (long)bat * SEQM * DIM;
        unsigned short* __restrict__ rng = ring[b];
        bool first = true;
        for (int k = 0; k < 12; k++) {
            if (k >= 3) {
                // ring-wrap safety: thr = 32k-9 (slot units, +1 margin).
                int thr = 32 * k - 9, g = 0;
                while (__hip_atomic_load(&cons_sl[b], __ATOMIC_ACQUIRE, WG) < thr) {
                    __builtin_amdgcn_s_sleep(2);
                    if (++g > (1 << 21)) break;
                }
            }
            // ---- B fragments for 32 cols (2 j-groups of 16) + b-norms ----
            frag_u bfrag[2][4];
            float bn[2];
            #pragma unroll
            for (int jg = 0; jg < 2; jg++) {
                const float* bp = Bb + (long)(32 * k + jg * 16 + l16) * DIM + q * 8;
                float s = 0.0f;
                #pragma unroll
                for (int kk = 0; kk < 4; kk++) {
                    float4 v0 = *(const float4*)(bp + kk * 32);
                    float4 v1 = *(const float4*)(bp + kk * 32 + 4);
                    bfrag[jg][kk].u[0] = bf16_pair(v0.x, v0.y);
                    bfrag[jg][kk].u[1] = bf16_pair(v0.z, v0.w);
                    bfrag[jg][kk].u[2] = bf16_pair(v1.x, v1.y);
                    bfrag[jg][kk].u[3] = bf16_pair(v1.z, v1.w);
                    s += v0.x*v0.x + v0.y*v0.y + v0.z*v0.z + v0.w*v0.w
                       + v1.x*v1.x + v1.y*v1.y + v1.z*v1.z + v1.w*v1.w;
                }
                s += __shfl_xor(s, 16, 64);
                s += __shfl_xor(s, 32, 64);
                bn[jg] = s;                // norm of this lane's j row
            }
            // ---- this wave's 8 si-groups, 1-deep A prefetch ----
            float4 c0v[4], c1v[4];
            {
                const float* ap = Ab + (long)(sbase * 16 + l16) * DIM + q * 8;
                #pragma unroll
                for (int kk = 0; kk < 4; kk++) {
                    c0v[kk] = *(const float4*)(ap + kk * 32);
                    c1v[kk] = *(const float4*)(ap + kk * 32 + 4);
                }
            }
            #pragma unroll
            for (int s8 = 0; s8 < 8; s8++) {
                const int si = sbase + s8;
                float4 n0[4], n1[4];
                if (s8 < 7) {              // prefetch next si-group
                    const float* ap = Ab + (long)((si + 1) * 16 + l16) * DIM + q * 8;
                    #pragma unroll
                    for (int kk = 0; kk < 4; kk++) {
                        n0[kk] = *(const float4*)(ap + kk * 32);
                        n1[kk] = *(const float4*)(ap + kk * 32 + 4);
                    }
                }
                frag_u afr[4];
                #pragma unroll
                for (int kk = 0; kk < 4; kk++) {
                    afr[kk].u[0] = bf16_pair(c0v[kk].x, c0v[kk].y);
                    afr[kk].u[1] = bf16_pair(c0v[kk].z, c0v[kk].w);
                    afr[kk].u[2] = bf16_pair(c1v[kk].x, c1v[kk].y);
                    afr[kk].u[3] = bf16_pair(c1v[kk].z, c1v[kk].w);
                }
                if (first) {               // this wave's normA slice (own rows)
                    float sa = 0.0f;
                    #pragma unroll
                    for (int kk = 0; kk < 4; kk++)
                        sa += c0v[kk].x*c0v[kk].x + c0v[kk].y*c0v[kk].y
                            + c0v[kk].z*c0v[kk].z + c0v[kk].w*c0v[kk].w
                            + c1v[kk].x*c1v[kk].x + c1v[kk].y*c1v[kk].y
                            + c1v[kk].z*c1v[kk].z + c1v[kk].w*c1v[kk].w;
                    sa += __shfl_xor(sa, 16, 64);
                    sa += __shfl_xor(sa, 32, 64);
                    if (q == 0) normA[b][si * 16 + l16] = sa;
                }
                f32x4 acc0 = {0.0f, 0.0f, 0.0f, 0.0f};
                f32x4 acc1 = {0.0f, 0.0f, 0.0f, 0.0f};
                #pragma unroll
                for (int kk = 0; kk < 4; kk++) {
                    acc0 = __builtin_amdgcn_mfma_f32_16x16x32_bf16(
                               afr[kk].v, bfrag[0][kk].v, acc0, 0, 0, 0);
                    acc1 = __builtin_amdgcn_mfma_f32_16x16x32_bf16(
                               afr[kk].v, bfrag[1][kk].v, acc1, 0, 0, 0);
                }
                if (first) asm volatile("s_waitcnt lgkmcnt(0)" ::: "memory");
                float4 an = *(const float4*)&normA[b][si * 16 + q * 4];
                #pragma unroll
                for (int jg = 0; jg < 2; jg++) {
                    int col = 32 * k + jg * 16 + l16;
                    int sl  = col;                      // col mod 100 (col<=383)
                    if (sl >= 200) sl -= 200;
                    if (sl >= 100) sl -= 100;
                    f32x4 ac = jg ? acc1 : acc0;
                    ushort4 pk;
                    pk.x = bf16_rne((an.x + bn[jg] - 2.0f * ac[0]) * LOG2E);
                    pk.y = bf16_rne((an.y + bn[jg] - 2.0f * ac[1]) * LOG2E);
                    pk.z = bf16_rne((an.z + bn[jg] - 2.0f * ac[2]) * LOG2E);
                    pk.w = bf16_rne((an.w + bn[jg] - 2.0f * ac[3]) * LOG2E);
                    *(ushort4*)&rng[sl * RSTRIDE + si * 16 + q * 4] = pk;
                }
                if (s8 < 7) {
                    #pragma unroll
                    for (int kk = 0; kk < 4; kk++) { c0v[kk] = n0[kk]; c1v[kk] = n1[kk]; }
                }
            }
            first = false;
            if (lane == 0)   // lane-0 only: counter==3 truly means all 3 waves
                __hip_atomic_fetch_add(&prod_done[b][k], 1, __ATOMIC_RELEASE, WG);
        }
        if (pidx == 0) {
            // pads: cols 384..387 -> slots 84..87 (overwrite cols 284..287,
            // dead after slot 346; first needed at refill slot 380). Gate 352.
            int g = 0;
            while (__hip_atomic_load(&cons_sl[b], __ATOMIC_ACQUIRE, WG) < 352) {
                __builtin_amdgcn_s_sleep(8);
                if (++g > (1 << 20)) break;
            }
            uint32_t pv = bf16_pair(KINF2, KINF2);
            #pragma unroll
            for (int c = 0; c < 4; c++) {
                uint32_t* p = (uint32_t*)&rng[(84 + c) * RSTRIDE + 6 * lane];
                p[0] = pv; p[1] = pv; p[2] = pv;
            }
            if (lane == 0)
                __hip_atomic_store(&prod_done[b][12], 3, __ATOMIC_RELEASE, WG);
        }
        return;
    }

    // ========== CONSUMERS (waves 0,4 -> both SIMD0): r10 body ================
    const int t = lane;
    {
        int g = 0;
        while (__hip_atomic_load(&prod_done[b][0], __ATOMIC_ACQUIRE, WG) < 3)
            if (++g > (1 << 22)) break;
    }
    __builtin_amdgcn_s_setprio(1);
    const unsigned short* __restrict__ ringT = ring[b] + 6 * t;

    float prev[6];                         // this lane's previous column values
    #pragma unroll
    for (int r = 0; r < 6; r++) prev[r] = KINF2;

    uint3 dslot[4];                        // FIFO: dslot[j] holds col (s - t + j)
    #pragma unroll
    for (int j = 0; j < 4; j++) {
        int c = j - t;
        int cc = c < 0 ? 0 : c;            // < RING, no wrap at init
        dslot[j] = *(const uint3*)(ringT + (long)cc * RSTRIDE);
    }

    float rcv_up = KINF2, rcv_diag = KINF2;
    float lane0_diag = 0.0f;               // R[0][0]; KINF2 afterwards
    const bool isl0 = (t == 0);
    int kdone = 0;

#define UNPACK(d, w)                                                        \
    d[0] = __uint_as_float(w.x << 16);                                      \
    d[1] = __uint_as_float(w.x & 0xFFFF0000u);                              \
    d[2] = __uint_as_float(w.y << 16);                                      \
    d[3] = __uint_as_float(w.y & 0xFFFF0000u);                              \
    d[4] = __uint_as_float(w.z << 16);                                      \
    d[5] = __uint_as_float(w.z & 0xFFFF0000u);

#define COLPASS(dX, diag0, upseed, LEFTV, NEWV)                             \
    {                                                                       \
        float Bp = (upseed), Fp = 1.0f;                                     \
        float Bv[6], Fv[6];                                                 \
        _Pragma("unroll")                                                   \
        for (int r = 0; r < 6; r++) {                                       \
            float vd = (r == 0) ? (diag0) : LEFTV[r - 1];                   \
            float vl = LEFTV[r];                                            \
            float m3 = fminf(fminf(vd, vl), Bp);     /* v_min3_f32 */       \
            float al = EXP2F(m3 - Bp);                                      \
            float be = EXP2F(m3 - vd) + EXP2F(m3 - vl);                     \
            float Fr = __builtin_fmaf(al, Fp, be);                          \
            float Br = dX[r] + m3;                                          \
            Bv[r] = Br; Fv[r] = Fr;                                         \
            Bp = Br; Fp = Fr;                                               \
        }                                                                   \
        _Pragma("unroll")                                                   \
        for (int r = 0; r < 6; r++)                                         \
            NEWV[r] = Bv[r] - LOG2F(Fv[r]);                                 \
    }

    // One column-slot: consume dslot[J], refill with col (S+4-t) (mod-100
    // ring), publish progress (relaxed, lane0), COLPASS, DPP boundary pass.
#define SLOT(J, S)                                                          \
    {                                                                       \
        uint3 w = dslot[J];                                                 \
        {   int cn = (S) + 4 - t;                                           \
            int cc = cn < 0 ? 0 : (cn > 387 ? 387 : cn);                    \
            int sl = cc;                                                    \
            if (sl >= 200) sl -= 200;                                       \
            if (sl >= 100) sl -= 100;                                       \
            dslot[J] = *(const uint3*)(ringT + (long)sl * RSTRIDE);         \
        }                                                                   \
        if (isl0)                          /* fresh progress each slot */   \
            __hip_atomic_store(&cons_sl[b], (S), __ATOMIC_RELAXED, WG);     \
        float d6[6];                                                        \
        UNPACK(d6, w)                                                       \
        float dg = isl0 ? lane0_diag : rcv_diag;                            \
        float up = isl0 ? KINF2 : rcv_up;                                   \
        COLPASS(d6, dg, up, prev, prev)                                     \
        rcv_diag = rcv_up;                                                  \
        rcv_up = dpp_shfl_up1(prev[5]);                                     \
        lane0_diag = KINF2;                                                 \
    }

    for (int i = 0; i < 111; i++) {        // slots 0..443
        int kr = (4 * i + 7) >> 5;         // chunk needed by this group's refills
        if (kr > 12) kr = 12;
        if (kr > kdone) {
            int g = 0;
            while (__hip_atomic_load(&prod_done[b][kr], __ATOMIC_ACQUIRE, WG) < 3)
                if (++g > (1 << 22)) break;
            kdone = kr;
        }
        SLOT(0, 4 * i)
        SLOT(1, 4 * i + 1)
        SLOT(2, 4 * i + 2)
        SLOT(3, 4 * i + 3)
        if ((i & 1) && t == 0)             // hard fence every 8 slots (release)
            __hip_atomic_store(&cons_sl[b], 4 * i + 3, __ATOMIC_RELEASE, WG);
    }
    SLOT(0, 444)                           // epilogue slots 444..446
    SLOT(1, 445)
    SLOT(2, 446)
#undef SLOT
#undef COLPASS
#undef UNPACK

    // lane 63, slot 446 = D col 383 (DP col 384): prev[5] = R[384][384]
    if (t == 63) out[bat] = prev[5] * LN2;
}

// ---------------------------------------------------------------------------
extern "C" void kernel_launch(void* const* d_in, const int* in_sizes, int n_in,
                              void* d_out, int out_size, void* d_ws, size_t ws_size,
                              hipStream_t stream) {
    (void)in_sizes; (void)n_in; (void)out_size; (void)d_ws; (void)ws_size;
    const float* a = (const float*)d_in[0];
    const float* b = (const float*)d_in[1];
    float* out = (float*)d_out;

    fused_dtw<<<dim3(BATCH / 2), dim3(512), 0, stream>>>(a, b, out);
}

// Round 13
// 199.273 us; speedup vs baseline: 1.5875x; 1.5875x over previous
//
#include <hip/hip_runtime.h>
#include <stdint.h>

// Problem constants (fixed by the reference setup_inputs)
#define BATCH 128
#define SEQN  384
#define SEQM  384
#define DIM   128
#define KINF   1000000.0f                 // reference pseudo-infinity (nat units)
#define LOG2E  1.4426950408889634f
#define LN2    0.6931471805599453f
#define KINF2  (KINF * LOG2E)             // pseudo-infinity in base-2-scaled units

// Fused producer/consumer geometry (round-10 verified)
#define RING    204                       // LDS ring capacity in D-columns
#define RSTRIDE 392                       // ushorts per ring column (conflict-free banks)

// hardware base-2 transcendentals (v_exp_f32 / v_log_f32)
#define EXP2F(x) __builtin_amdgcn_exp2f(x)
#define LOG2F(x) __builtin_amdgcn_logf(x)

#define WG __HIP_MEMORY_SCOPE_WORKGROUP

typedef __attribute__((ext_vector_type(8))) short bf16x8;   // 8 bf16 = 4 VGPRs (MFMA A/B frag)
typedef __attribute__((ext_vector_type(4))) float f32x4;    // MFMA C/D frag

__device__ __forceinline__ unsigned short bf16_rne(float x) {
    uint32_t u = __float_as_uint(x);
    u += 0x7FFFu + ((u >> 16) & 1u);
    return (unsigned short)(u >> 16);
}
__device__ __forceinline__ uint32_t bf16_pair(float x, float y) {
    uint32_t ux = __float_as_uint(x); ux += 0x7FFFu + ((ux >> 16) & 1u);
    uint32_t uy = __float_as_uint(y); uy += 0x7FFFu + ((uy >> 16) & 1u);
    return (ux >> 16) | (uy & 0xFFFF0000u);
}

// DPP wavefront-shift-right-by-1: lane n <- lane n-1 (== __shfl_up(x,1,64)).
__device__ __forceinline__ float dpp_shfl_up1(float x) {
    return __int_as_float(__builtin_amdgcn_update_dpp(
        0, (int)__float_as_uint(x), 0x138 /*WAVE_SHR1*/, 0xF, 0xF, false));
}

union frag_u { bf16x8 v; uint32_t u[4]; };

// ---------------------------------------------------------------------------
// Fused kernel: one block per batch, 8 waves (512 thr), 1 block/CU.
// Structure = round-10 VERBATIM except the consumer recurrence: PAIR-DOMAIN
// (r6-verified math), with the r12 in-place aliasing bug FIXED:
//   r12 bug: cell r+1's diag read prevB[r] AFTER cell r overwrote it (new
//   column value instead of previous column's) -> absmax 65024.
//   Fix: carry registers cdB/cdF save the OLD prevB[r]/prevF[r] before the
//   overwrite and feed cell r+1's diag — exact r6 dataflow, in-place storage.
// Per cell: m = min3(...); F' = exp2-weighted sum (3 exp2, 0 log2);
// B' = d + m; F normalized to [1,2) by exponent bit-extraction (no trans).
// One log2 per batch at the output. Boundary pass = 2 DPP shifts (B and F).
// ---------------------------------------------------------------------------
__global__ __launch_bounds__(512) void fused_dtw(
        const float* __restrict__ A, const float* __restrict__ B,
        float* __restrict__ out) {
    __shared__ __align__(16) unsigned short ring[RING * RSTRIDE]; // 159,936 B
    __shared__ __align__(16) float normA[SEQN];                   //   1,536 B
    __shared__ int prod_done[16];
    __shared__ int cons_sl;

    const int bat  = blockIdx.x;
    const int tid  = threadIdx.x;
    const int wv   = tid >> 6;
    const int lane = tid & 63;

    if (tid < 16) prod_done[tid] = 0;
    if (tid == 16) cons_sl = -1;
    __syncthreads();                       // only block-wide sync in the kernel

    if (wv == 4) {
        // ================= PAD WRITER (wave 4, shares SIMD0) =================
        int g = 0;
        while (__hip_atomic_load(&cons_sl, __ATOMIC_ACQUIRE, WG) < 248) {
            __builtin_amdgcn_s_sleep(8);   // ~512 cyc naps: no issue pressure
            if (++g > (1 << 20)) break;
        }
        uint32_t pv = bf16_pair(KINF2, KINF2);
        #pragma unroll
        for (int c = 0; c < 4; c++) {
            uint32_t* p = (uint32_t*)&ring[(384 - RING + c) * RSTRIDE + 6 * lane];
            p[0] = pv; p[1] = pv; p[2] = pv;
        }
        if (lane == 0)
            __hip_atomic_fetch_add(&prod_done[12], 6, __ATOMIC_RELEASE, WG);
        return;
    }

    if (wv != 0) {
        // ============== PRODUCERS (waves 1,2,3,5,6,7 -> pidx 0..5) ===========
        const int pidx  = (wv < 4) ? (wv - 1) : (wv - 2);
        const int sbase = pidx * 4;        // this wave's 4 si-groups (of 24)
        const int l16 = lane & 15, q = lane >> 4;
        const float* __restrict__ Ab = A + (long)bat * SEQN * DIM;
        const float* __restrict__ Bb = B + (long)bat * SEQM * DIM;
        bool first = true;
        for (int k = 0; k < 12; k++) {
            if (k >= 6) {
                // ring-wrap safety, slot units: thr = 32k-110.
                int thr = 32 * k - 110, g = 0;
                while (__hip_atomic_load(&cons_sl, __ATOMIC_ACQUIRE, WG) < thr) {
                    __builtin_amdgcn_s_sleep(2);
                    if (++g > (1 << 21)) break;
                }
            }
            // ---- B fragments for 32 cols (2 j-groups of 16) + b-norms ----
            frag_u bfrag[2][4];
            float bn[2];
            #pragma unroll
            for (int jg = 0; jg < 2; jg++) {
                const float* bp = Bb + (long)(32 * k + jg * 16 + l16) * DIM + q * 8;
                float s = 0.0f;
                #pragma unroll
                for (int kk = 0; kk < 4; kk++) {
                    float4 v0 = *(const float4*)(bp + kk * 32);
                    float4 v1 = *(const float4*)(bp + kk * 32 + 4);
                    bfrag[jg][kk].u[0] = bf16_pair(v0.x, v0.y);
                    bfrag[jg][kk].u[1] = bf16_pair(v0.z, v0.w);
                    bfrag[jg][kk].u[2] = bf16_pair(v1.x, v1.y);
                    bfrag[jg][kk].u[3] = bf16_pair(v1.z, v1.w);
                    s += v0.x*v0.x + v0.y*v0.y + v0.z*v0.z + v0.w*v0.w
                       + v1.x*v1.x + v1.y*v1.y + v1.z*v1.z + v1.w*v1.w;
                }
                s += __shfl_xor(s, 16, 64);
                s += __shfl_xor(s, 32, 64);
                bn[jg] = s;                // norm of this lane's j row
            }
            // ---- this wave's 4 si-groups, 1-deep A prefetch ----
            float4 c0v[4], c1v[4];
            {
                const float* ap = Ab + (long)(sbase * 16 + l16) * DIM + q * 8;
                #pragma unroll
                for (int kk = 0; kk < 4; kk++) {
                    c0v[kk] = *(const float4*)(ap + kk * 32);
                    c1v[kk] = *(const float4*)(ap + kk * 32 + 4);
                }
            }
            #pragma unroll
            for (int s4 = 0; s4 < 4; s4++) {
                const int si = sbase + s4;
                float4 n0[4], n1[4];
                if (s4 < 3) {              // prefetch next si-group
                    const float* ap = Ab + (long)((si + 1) * 16 + l16) * DIM + q * 8;
                    #pragma unroll
                    for (int kk = 0; kk < 4; kk++) {
                        n0[kk] = *(const float4*)(ap + kk * 32);
                        n1[kk] = *(const float4*)(ap + kk * 32 + 4);
                    }
                }
                frag_u afr[4];
                #pragma unroll
                for (int kk = 0; kk < 4; kk++) {
                    afr[kk].u[0] = bf16_pair(c0v[kk].x, c0v[kk].y);
                    afr[kk].u[1] = bf16_pair(c0v[kk].z, c0v[kk].w);
                    afr[kk].u[2] = bf16_pair(c1v[kk].x, c1v[kk].y);
                    afr[kk].u[3] = bf16_pair(c1v[kk].z, c1v[kk].w);
                }
                if (first) {               // this wave's normA slice (own rows)
                    float sa = 0.0f;
                    #pragma unroll
                    for (int kk = 0; kk < 4; kk++)
                        sa += c0v[kk].x*c0v[kk].x + c0v[kk].y*c0v[kk].y
                            + c0v[kk].z*c0v[kk].z + c0v[kk].w*c0v[kk].w
                            + c1v[kk].x*c1v[kk].x + c1v[kk].y*c1v[kk].y
                            + c1v[kk].z*c1v[kk].z + c1v[kk].w*c1v[kk].w;
                    sa += __shfl_xor(sa, 16, 64);
                    sa += __shfl_xor(sa, 32, 64);
                    if (q == 0) normA[si * 16 + l16] = sa;
                }
                f32x4 acc0 = {0.0f, 0.0f, 0.0f, 0.0f};
                f32x4 acc1 = {0.0f, 0.0f, 0.0f, 0.0f};
                #pragma unroll
                for (int kk = 0; kk < 4; kk++) {
                    acc0 = __builtin_amdgcn_mfma_f32_16x16x32_bf16(
                               afr[kk].v, bfrag[0][kk].v, acc0, 0, 0, 0);
                    acc1 = __builtin_amdgcn_mfma_f32_16x16x32_bf16(
                               afr[kk].v, bfrag[1][kk].v, acc1, 0, 0, 0);
                }
                if (first) asm volatile("s_waitcnt lgkmcnt(0)" ::: "memory");
                float4 an = *(const float4*)&normA[si * 16 + q * 4];
                #pragma unroll
                for (int jg = 0; jg < 2; jg++) {
                    int col  = 32 * k + jg * 16 + l16;
                    int slot = col >= RING ? col - RING : col;
                    f32x4 ac = jg ? acc1 : acc0;
                    ushort4 pk;
                    pk.x = bf16_rne((an.x + bn[jg] - 2.0f * ac[0]) * LOG2E);
                    pk.y = bf16_rne((an.y + bn[jg] - 2.0f * ac[1]) * LOG2E);
                    pk.z = bf16_rne((an.z + bn[jg] - 2.0f * ac[2]) * LOG2E);
                    pk.w = bf16_rne((an.w + bn[jg] - 2.0f * ac[3]) * LOG2E);
                    *(ushort4*)&ring[slot * RSTRIDE + si * 16 + q * 4] = pk;
                }
                if (s4 < 3) {
                    #pragma unroll
                    for (int kk = 0; kk < 4; kk++) { c0v[kk] = n0[kk]; c1v[kk] = n1[kk]; }
                }
            }
            first = false;
            if (lane == 0)   // lane-0 only: counter==6 truly means all 6 waves
                __hip_atomic_fetch_add(&prod_done[k], 1, __ATOMIC_RELEASE, WG);
        }
        return;
    }

    // ==== CONSUMER (wave 0): 1-col/lane skew, PAIR-DOMAIN cells, DPP pass ====
    const int t = lane;
    {
        int g = 0;
        while (__hip_atomic_load(&prod_done[0], __ATOMIC_ACQUIRE, WG) < 6)
            if (++g > (1 << 22)) break;
    }
    __builtin_amdgcn_s_setprio(1);         // favor the DP wave on its SIMD
    const unsigned short* __restrict__ ringT = ring + 6 * t;

    // prev column state as exact pairs: v = B - log2 F, F in [1,2)
    float prevB[6], prevF[6];
    #pragma unroll
    for (int r = 0; r < 6; r++) { prevB[r] = KINF2; prevF[r] = 1.0f; }

    uint3 dslot[4];                        // FIFO: dslot[j] holds col (s - t + j)
    #pragma unroll
    for (int j = 0; j < 4; j++) {
        int c = j - t;
        int cc = c < 0 ? 0 : c;            // clamp low (< RING always here)
        dslot[j] = *(const uint3*)(ringT + (long)cc * RSTRIDE);
    }

    float upB = KINF2, upF = 1.0f;         // lane t-1 bottom of col (s-t)
    float dgB = KINF2, dgF = 1.0f;         // lane t-1 bottom of col (s-t-1)
    float l0dB = 0.0f, l0dF = 1.0f;        // R[0][0]; (KINF2,1) afterwards
    const bool isl0 = (t == 0);
    int kdone = 0;

#define UNPACK(d, w)                                                        \
    d[0] = __uint_as_float(w.x << 16);                                      \
    d[1] = __uint_as_float(w.x & 0xFFFF0000u);                              \
    d[2] = __uint_as_float(w.y << 16);                                      \
    d[3] = __uint_as_float(w.y & 0xFFFF0000u);                              \
    d[4] = __uint_as_float(w.z << 16);                                      \
    d[5] = __uint_as_float(w.z & 0xFFFF0000u);

    // Pair-domain column pass (r6-verified math): 3 exp2, 0 log2 per cell.
    // ALIASING FIX vs r12: cdB/cdF carry the OLD prevB[r]/prevF[r] (previous
    // column, row r) into cell r+1's diag before the in-place overwrite.
#define COLPASS(dX, dgB_, dgF_, upB_, upF_)                                 \
    {                                                                       \
        float Bp = (upB_), Fp = (upF_);                                     \
        float cdB = (dgB_), cdF = (dgF_);                                   \
        _Pragma("unroll")                                                   \
        for (int r = 0; r < 6; r++) {                                       \
            float vdB = cdB, vdF = cdF;                                     \
            float vlB = prevB[r], vlF = prevF[r];                           \
            float m3 = fminf(fminf(vdB, vlB), Bp);   /* v_min3_f32 */       \
            float Fr = EXP2F(m3 - Bp) * Fp;                                 \
            Fr = __builtin_fmaf(EXP2F(m3 - vdB), vdF, Fr);                  \
            Fr = __builtin_fmaf(EXP2F(m3 - vlB), vlF, Fr);                  \
            float Br = dX[r] + m3;                                          \
            cdB = vlB; cdF = vlF;          /* old left -> next cell's diag */\
            uint32_t fb = __float_as_uint(Fr);                              \
            int e = (int)(fb >> 23) - 127;                                  \
            prevB[r] = Br - (float)e;                                       \
            prevF[r] = __uint_as_float((fb & 0x007FFFFFu) | 0x3F800000u);   \
            Bp = Br; Fp = Fr;      /* unnormalized within the column */     \
        }                                                                   \
    }

    // One column-slot: consume dslot[J], refill with col (S+4-t), COLPASS,
    // rotate boundary pairs, two DPP shifts (B and F).
#define SLOT(J, S)                                                          \
    {                                                                       \
        uint3 w = dslot[J];                                                 \
        {   int cn = (S) + 4 - t;                                           \
            int cc = cn < 0 ? 0 : (cn > 387 ? 387 : cn);                    \
            int sl = cc >= RING ? cc - RING : cc;                           \
            dslot[J] = *(const uint3*)(ringT + (long)sl * RSTRIDE);         \
        }                                                                   \
        float d6[6];                                                        \
        UNPACK(d6, w)                                                       \
        float dB = isl0 ? l0dB : dgB;                                       \
        float dF = isl0 ? l0dF : dgF;                                       \
        float uB = isl0 ? KINF2 : upB;                                      \
        float uF = isl0 ? 1.0f  : upF;                                      \
        COLPASS(d6, dB, dF, uB, uF)                                         \
        dgB = upB; dgF = upF;                                               \
        upB = dpp_shfl_up1(prevB[5]);                                       \
        upF = dpp_shfl_up1(prevF[5]);                                       \
        l0dB = KINF2; l0dF = 1.0f;                                          \
    }

    for (int i = 0; i < 111; i++) {        // slots 0..443
        int kr = (4 * i + 7) >> 5;         // chunk needed by this group's refills
        if (kr > 12) kr = 12;
        if (kr > kdone) {
            int g = 0;
            while (__hip_atomic_load(&prod_done[kr], __ATOMIC_ACQUIRE, WG) < 6)
                if (++g > (1 << 22)) break;
            kdone = kr;
        }
        SLOT(0, 4 * i)
        SLOT(1, 4 * i + 1)
        SLOT(2, 4 * i + 2)
        SLOT(3, 4 * i + 3)
        if ((i & 1) && t == 0)             // publish every 8 slots (release =>
            __hip_atomic_store(&cons_sl, 4 * i + 3,  // lgkm drain: reads durable)
                               __ATOMIC_RELEASE, WG);
    }
    SLOT(0, 444)                           // epilogue slots 444..446
    SLOT(1, 445)
    SLOT(2, 446)
#undef SLOT
#undef COLPASS
#undef UNPACK

    // lane 63, slot 446 = D col 383 (DP col 384): pair -> v, one log2/batch
    if (t == 63) out[bat] = (prevB[5] - LOG2F(prevF[5])) * LN2;
}

// ---------------------------------------------------------------------------
extern "C" void kernel_launch(void* const* d_in, const int* in_sizes, int n_in,
                              void* d_out, int out_size, void* d_ws, size_t ws_size,
                              hipStream_t stream) {
    (void)in_sizes; (void)n_in; (void)out_size; (void)d_ws; (void)ws_size;
    const float* a = (const float*)d_in[0];
    const float* b = (const float*)d_in[1];
    float* out = (float*)d_out;

    fused_dtw<<<dim3(BATCH), dim3(512), 0, stream>>>(a, b, out);
}